// Round 1
// baseline (34.817 us; speedup 1.0000x reference)
//
#include <hip/hip_runtime.h>

// SubpixelReshuffleLayer: out[b, 2i+r2, 2j+r1, g] = x[b, i, j, 4g + 2r1 + r2]
// x: [32,256,256,12] f32, out: [32,512,512,3] f32.
//
// Flat-index block structure: input floats [6144*t, 6144*(t+1)) (2 input rows)
// map exactly to output floats [6144*t, 6144*(t+1)) (4 output rows). Each
// block permutes one 24 KB tile via LDS:
//   phase 1: 6x perfectly-coalesced global float4 loads -> scattered LDS writes
//   phase 2: contiguous ds_read_b128 -> perfectly-coalesced global float4 stores

#define TILE_FLOATS 6144   // 512 input pixels * 12 ch = 4 output rows * 1536
#define TILE_VEC4   (TILE_FLOATS / 4)   // 1536 float4 per tile
#define THREADS     256
#define VEC_PER_THR (TILE_VEC4 / THREADS)  // 6

__global__ __launch_bounds__(THREADS)
void subpixel_reshuffle_kernel(const float4* __restrict__ in,
                               float4* __restrict__ out) {
    __shared__ float lds[TILE_FLOATS];

    const int t = threadIdx.x;
    const long long tile = blockIdx.x;
    const float4* in_t  = in  + tile * TILE_VEC4;
    float4*       out_t = out + tile * TILE_VEC4;

    // Phase 1: coalesced global reads, scattered LDS writes.
    // float4 q holds channels [4g, 4g+3] of local pixel p (q = 3p + g):
    //   component .x -> (r1=0,r2=0), .y -> (r1=0,r2=1),
    //             .z -> (r1=1,r2=0), .w -> (r1=1,r2=1)
    // LDS position (output order within tile):
    //   fo = (2*ir + r2)*1536 + 6*j + 3*r1 + g,  p = ir*256 + j
    #pragma unroll
    for (int k = 0; k < VEC_PER_THR; ++k) {
        const int q = k * THREADS + t;        // 0..1535
        const float4 v = in_t[q];
        const int p = q / 3;                  // local pixel 0..511
        const int g = q - 3 * p;              // channel group 0..2
        const int ir = p >> 8;                // local input row 0..1
        const int j  = p & 255;               // column
        const int base = ir * 3072 + 6 * j + g;
        lds[base]          = v.x;  // r1=0, r2=0
        lds[base + 3]      = v.z;  // r1=1, r2=0
        lds[base + 1536]   = v.y;  // r1=0, r2=1
        lds[base + 1539]   = v.w;  // r1=1, r2=1
    }

    __syncthreads();

    // Phase 2: contiguous LDS reads (b128), coalesced global float4 stores.
    #pragma unroll
    for (int k = 0; k < VEC_PER_THR; ++k) {
        const int q = k * THREADS + t;
        out_t[q] = *reinterpret_cast<const float4*>(&lds[4 * q]);
    }
}

extern "C" void kernel_launch(void* const* d_in, const int* in_sizes, int n_in,
                              void* d_out, int out_size, void* d_ws, size_t ws_size,
                              hipStream_t stream) {
    const float* x = (const float*)d_in[0];
    float* y = (float*)d_out;
    const int n_tiles = in_sizes[0] / TILE_FLOATS;   // 4096
    subpixel_reshuffle_kernel<<<n_tiles, THREADS, 0, stream>>>(
        (const float4*)x, (float4*)y);
}